// Round 1
// baseline (348.903 us; speedup 1.0000x reference)
//
#include <hip/hip_runtime.h>
#include <stdint.h>

typedef _Float16 f16;
typedef _Float16 f16x2 __attribute__((ext_vector_type(2)));
typedef _Float16 f16x4 __attribute__((ext_vector_type(4)));
typedef _Float16 f16x8 __attribute__((ext_vector_type(8)));
typedef float f32x4 __attribute__((ext_vector_type(4)));

typedef __attribute__((address_space(1))) void gvoid;
typedef __attribute__((address_space(3))) void lvoid;

#define NROWS 4096
#define DIMIN 1536
#define DMLP 512
#define FDIM 256
#define NCLS 10000
#define NPAD 10112   // 79 * 128

__device__ __forceinline__ void load_lds16(const void* g, void* l) {
    // async global->LDS, 16B per lane; LDS dest = wave-uniform base + lane*16
    __builtin_amdgcn_global_load_lds((gvoid*)g, (lvoid*)l, 16, 0, 0);
}

// ---------------------------------------------------------------------------
// Generic fp16 GEMM: C[M,N] = A[M,K] @ Bt[N,K]^T (+bias), m97-style structure.
// Tiles: 128x128 per block (256 thr = 4 waves, each wave 64x64 via 4x4 MFMA
// 16x16x32_f16). K must be /32, M,N grid-covered by 128.
// ---------------------------------------------------------------------------
__global__ __launch_bounds__(256) void gemm_bt_f16(
    const f16* __restrict__ A, const f16* __restrict__ Bt,
    float* __restrict__ C, const float* __restrict__ bias,
    int K, int ldc, int Nstore)
{
    __shared__ f16 As[128 * 32];   // 8 KB
    __shared__ f16 Bs[128 * 32];   // 8 KB

    const int tid  = threadIdx.x;
    const int lane = tid & 63;
    const int w    = tid >> 6;
    const int wm   = (w >> 1) * 64;
    const int wn   = (w & 1) * 64;
    const int row0 = blockIdx.x * 128;
    const int col0 = blockIdx.y * 128;
    const int quad = lane >> 4;
    const int r16  = lane & 15;

    f32x4 acc[4][4] = {};

    // staging: chunk = 16B; chunk c -> row c>>2, 16B-group c&3
    const int c0 = tid, c1 = tid + 256;
    const int ar0 = c0 >> 2, ag0 = (c0 & 3) * 8;
    const int ar1 = c1 >> 2, ag1 = (c1 & 3) * 8;
    const f16* pa0 = A  + (size_t)(row0 + ar0) * K + ag0;
    const f16* pa1 = A  + (size_t)(row0 + ar1) * K + ag1;
    const f16* pb0 = Bt + (size_t)(col0 + ar0) * K + ag0;
    const f16* pb1 = Bt + (size_t)(col0 + ar1) * K + ag1;

    for (int k0 = 0; k0 < K; k0 += 32) {
        load_lds16(pa0 + k0, &As[c0 * 8]);
        load_lds16(pa1 + k0, &As[c1 * 8]);
        load_lds16(pb0 + k0, &Bs[c0 * 8]);
        load_lds16(pb1 + k0, &Bs[c1 * 8]);
        __syncthreads();   // compiler drains vmcnt before barrier

        f16x8 af[4], bq[4];
#pragma unroll
        for (int mi = 0; mi < 4; ++mi)
            af[mi] = *(const f16x8*)&As[(wm + mi * 16 + r16) * 32 + quad * 8];
#pragma unroll
        for (int ni = 0; ni < 4; ++ni)
            bq[ni] = *(const f16x8*)&Bs[(wn + ni * 16 + r16) * 32 + quad * 8];
#pragma unroll
        for (int mi = 0; mi < 4; ++mi)
#pragma unroll
            for (int ni = 0; ni < 4; ++ni)
                acc[mi][ni] = __builtin_amdgcn_mfma_f32_16x16x32_f16(
                    af[mi], bq[ni], acc[mi][ni], 0, 0, 0);
        __syncthreads();
    }

    // C/D layout: col = lane&15, row = quad*4 + reg
#pragma unroll
    for (int mi = 0; mi < 4; ++mi) {
#pragma unroll
        for (int ni = 0; ni < 4; ++ni) {
            int col = col0 + wn + ni * 16 + r16;
            if (col < Nstore) {
                float bv = bias ? bias[col] : 0.0f;
                int rowb = row0 + wm + mi * 16 + quad * 4;
#pragma unroll
                for (int r = 0; r < 4; ++r)
                    C[(size_t)(rowb + r) * ldc + col] = acc[mi][ni][r] + bv;
            }
        }
    }
}

// ---------------------------------------------------------------------------
__global__ void zero_k(float* __restrict__ p, int n) {
    int i = blockIdx.x * 256 + threadIdx.x;
    if (i < n) p[i] = 0.0f;
}

__global__ void f32_to_f16_k(const float* __restrict__ in, f16* __restrict__ out, int n4) {
    int i = blockIdx.x * 256 + threadIdx.x;
    if (i >= n4) return;
    float4 v = *(const float4*)&in[(size_t)i * 4];
    f16x4 o = {(f16)v.x, (f16)v.y, (f16)v.z, (f16)v.w};
    *(f16x4*)&out[(size_t)i * 4] = o;
}

// in [R,C] fp32 -> out [C,R] fp16 (coalesced writes, strided reads via L2)
__global__ void transpose_to_f16_k(const float* __restrict__ in, f16* __restrict__ out, int R, int C) {
    int idx = blockIdx.x * 256 + threadIdx.x;
    if (idx >= R * C) return;
    int n = idx / R, k = idx - n * R;
    out[idx] = (f16)in[(size_t)k * C + n];
}

// column sums/sumsq of h [4096,512]; 128 blocks x 256 thr, 2 cols/thread
__global__ void bn_stats_k(const float* __restrict__ h, float* __restrict__ sums, float* __restrict__ sqs) {
    int t = threadIdx.x, b = blockIdx.x;
    int c = t * 2;
    float s0 = 0.f, s1 = 0.f, q0 = 0.f, q1 = 0.f;
    for (int r = b; r < NROWS; r += 128) {
        float2 v = *(const float2*)&h[(size_t)r * DMLP + c];
        s0 += v.x; s1 += v.y; q0 += v.x * v.x; q1 += v.y * v.y;
    }
    atomicAdd(&sums[c], s0);
    atomicAdd(&sums[c + 1], s1);
    atomicAdd(&sqs[c], q0);
    atomicAdd(&sqs[c + 1], q1);
}

// BN apply + ReLU + cast to fp16; 2 elems/thread (float2)
__global__ void bn_apply_k(const float* __restrict__ h, const float* __restrict__ sums,
                           const float* __restrict__ sqs, const float* __restrict__ gamma,
                           const float* __restrict__ beta, f16* __restrict__ out) {
    int i = blockIdx.x * 256 + threadIdx.x;     // over 4096*512/2
    int c = (i & 255) * 2;
    float2 v = *(const float2*)&h[(size_t)i * 2];
    const float inv_n = 1.0f / 4096.0f;
    float mu0 = sums[c] * inv_n, mu1 = sums[c + 1] * inv_n;
    float var0 = fmaxf(sqs[c] * inv_n - mu0 * mu0, 0.0f);
    float var1 = fmaxf(sqs[c + 1] * inv_n - mu1 * mu1, 0.0f);
    float sc0 = rsqrtf(var0 + 1e-5f) * gamma[c];
    float sc1 = rsqrtf(var1 + 1e-5f) * gamma[c + 1];
    float o0 = fmaxf((v.x - mu0) * sc0 + beta[c], 0.0f);
    float o1 = fmaxf((v.y - mu1) * sc1 + beta[c + 1], 0.0f);
    f16x2 o = {(f16)o0, (f16)o1};
    *(f16x2*)&out[(size_t)i * 2] = o;
}

// row-wise L2 normalize out2[4096,256] -> feat fp32 + fp16; one wave/row
__global__ void l2norm_k(const float* __restrict__ X, float* __restrict__ Y, f16* __restrict__ Yh) {
    int wv = (blockIdx.x * 256 + threadIdx.x) >> 6;
    int lane = threadIdx.x & 63;
    float4 v = *(const float4*)&X[(size_t)wv * FDIM + lane * 4];
    float s = v.x * v.x + v.y * v.y + v.z * v.z + v.w * v.w;
#pragma unroll
    for (int off = 32; off > 0; off >>= 1) s += __shfl_xor(s, off);
    float inv = 1.0f / fmaxf(sqrtf(s), 1e-12f);
    float4 o = {v.x * inv, v.y * inv, v.z * inv, v.w * inv};
    *(float4*)&Y[(size_t)wv * FDIM + lane * 4] = o;
    f16x4 oh = {(f16)o.x, (f16)o.y, (f16)o.z, (f16)o.w};
    *(f16x4*)&Yh[(size_t)wv * FDIM + lane * 4] = oh;
}

// memory_pt -> fp16 padded [NPAD,256]; pad rows zeroed
__global__ void mem_init_k(const float* __restrict__ mp, f16* __restrict__ memh) {
    int i = blockIdx.x * 256 + threadIdx.x;     // NPAD*64 threads
    int row = i >> 6, c = (i & 63) * 4;
    f16x4 o = {(f16)0.f, (f16)0.f, (f16)0.f, (f16)0.f};
    if (row < NCLS) {
        float4 v = *(const float4*)&mp[(size_t)row * FDIM + c];
        o = (f16x4){(f16)v.x, (f16)v.y, (f16)v.z, (f16)v.w};
    }
    *(f16x4*)&memh[(size_t)row * FDIM + c] = o;
}

// per-label sequential momentum chain; one wave per label, fp32 math
__global__ void chain_k(const int* __restrict__ label, const float* __restrict__ feat,
                        const float* __restrict__ mp, f16* __restrict__ memh) {
    int y = (blockIdx.x * 256 + threadIdx.x) >> 6;
    int lane = threadIdx.x & 63;
    if (y >= NCLS) return;
    float4 m = *(const float4*)&mp[(size_t)y * FDIM + lane * 4];
    bool touched = false;
    for (int g = 0; g < 64; ++g) {
        int lab = label[g * 64 + lane];
        unsigned long long mask = __ballot(lab == y);
        while (mask) {
            int b = __builtin_ctzll(mask);
            mask &= mask - 1;
            int i = g * 64 + b;
            float4 x = *(const float4*)&feat[(size_t)i * FDIM + lane * 4];
            m.x = 0.9f * m.x + 0.1f * x.x;
            m.y = 0.9f * m.y + 0.1f * x.y;
            m.z = 0.9f * m.z + 0.1f * x.z;
            m.w = 0.9f * m.w + 0.1f * x.w;
            float s = m.x * m.x + m.y * m.y + m.z * m.z + m.w * m.w;
#pragma unroll
            for (int off = 32; off > 0; off >>= 1) s += __shfl_xor(s, off);
            float inv = 1.0f / fmaxf(sqrtf(s), 1e-12f);
            m.x *= inv; m.y *= inv; m.z *= inv; m.w *= inv;
            touched = true;
        }
    }
    if (touched) {
        f16x4 o = {(f16)m.x, (f16)m.y, (f16)m.z, (f16)m.w};
        *(f16x4*)&memh[(size_t)y * FDIM + lane * 4] = o;
    }
}

// ---------------------------------------------------------------------------
extern "C" void kernel_launch(void* const* d_in, const int* in_sizes, int n_in,
                              void* d_out, int out_size, void* d_ws, size_t ws_size,
                              hipStream_t stream) {
    const float* feat_in = (const float*)d_in[0];
    const int*   label   = (const int*)d_in[1];
    const float* W1      = (const float*)d_in[2];
    const float* b1      = (const float*)d_in[3];
    const float* gamma   = (const float*)d_in[4];
    const float* beta    = (const float*)d_in[5];
    const float* W2      = (const float*)d_in[6];
    const float* b2      = (const float*)d_in[7];
    const float* mp      = (const float*)d_in[8];
    float* out = (float*)d_out;

    char* w = (char*)d_ws;
    f16* A1h   = (f16*)w;   w += (size_t)NROWS * DIMIN * 2;   // 12.6 MB
    f16* W1t   = (f16*)w;   w += (size_t)DMLP * DIMIN * 2;    // 1.6 MB
    f16* W2t   = (f16*)w;   w += (size_t)FDIM * DMLP * 2;     // 0.26 MB
    float* h   = (float*)w; w += (size_t)NROWS * DMLP * 4;    // 8.4 MB
    f16* h2    = (f16*)w;   w += (size_t)NROWS * DMLP * 2;    // 4.2 MB
    float* out2= (float*)w; w += (size_t)NROWS * FDIM * 4;    // 4.2 MB
    float* feat= (float*)w; w += (size_t)NROWS * FDIM * 4;    // 4.2 MB
    f16* feath = (f16*)w;   w += (size_t)NROWS * FDIM * 2;    // 2.1 MB
    f16* memh  = (f16*)w;   w += (size_t)NPAD * FDIM * 2;     // 5.2 MB
    float* sums= (float*)w; w += DMLP * 4;
    float* sqs = (float*)w; w += DMLP * 4;

    // stage 0: conversions + stat zeroing
    zero_k<<<4, 256, 0, stream>>>(sums, 2 * DMLP);   // sums+sqs contiguous
    f32_to_f16_k<<<(NROWS * DIMIN / 4) / 256, 256, 0, stream>>>(feat_in, A1h, NROWS * DIMIN / 4);
    transpose_to_f16_k<<<(DIMIN * DMLP) / 256, 256, 0, stream>>>(W1, W1t, DIMIN, DMLP);
    transpose_to_f16_k<<<(DMLP * FDIM) / 256, 256, 0, stream>>>(W2, W2t, DMLP, FDIM);

    // GEMM1: h = feat_in @ W1 + b1
    {
        dim3 g(NROWS / 128, DMLP / 128);
        gemm_bt_f16<<<g, 256, 0, stream>>>(A1h, W1t, h, b1, DIMIN, DMLP, DMLP);
    }

    // BN
    bn_stats_k<<<128, 256, 0, stream>>>(h, sums, sqs);
    bn_apply_k<<<(NROWS * DMLP / 2) / 256, 256, 0, stream>>>(h, sums, sqs, gamma, beta, h2);

    // GEMM2: out2 = h2 @ W2 + b2
    {
        dim3 g(NROWS / 128, FDIM / 128);
        gemm_bt_f16<<<g, 256, 0, stream>>>(h2, W2t, out2, b2, DMLP, FDIM, FDIM);
    }

    // feat = l2norm(out2)
    l2norm_k<<<NROWS / 4, 256, 0, stream>>>(out2, feat, feath);

    // memory bank: init + per-label chains
    mem_init_k<<<NPAD * 64 / 256, 256, 0, stream>>>(mp, memh);
    chain_k<<<NCLS / 4, 256, 0, stream>>>(label, feat, mp, memh);

    // GEMM3: sim = feat @ mem^T   [4096, 10000]
    {
        dim3 g(NROWS / 128, NPAD / 128);
        gemm_bt_f16<<<g, 256, 0, stream>>>(feath, memh, out, nullptr, FDIM, NCLS, NCLS);
    }
}

// Round 2
// 322.769 us; speedup vs baseline: 1.0810x; 1.0810x over previous
//
#include <hip/hip_runtime.h>
#include <stdint.h>

typedef _Float16 f16;
typedef _Float16 f16x2 __attribute__((ext_vector_type(2)));
typedef _Float16 f16x4 __attribute__((ext_vector_type(4)));
typedef _Float16 f16x8 __attribute__((ext_vector_type(8)));
typedef float f32x4 __attribute__((ext_vector_type(4)));

typedef __attribute__((address_space(1))) void gvoid;
typedef __attribute__((address_space(3))) void lvoid;

#define NROWS 4096
#define DIMIN 1536
#define DMLP 512
#define FDIM 256
#define NCLS 10000
#define NPAD 10112   // 79 * 128

__device__ __forceinline__ void load_lds16(const void* g, void* l) {
    // async global->LDS, 16B per lane; LDS dest = wave-uniform base + lane*16
    __builtin_amdgcn_global_load_lds((gvoid*)g, (lvoid*)l, 16, 0, 0);
}

// ---------------------------------------------------------------------------
// fp16 GEMM: C[M,N] = A[M,K] @ Bt[N,K]^T (+bias).
// Tile TM x TN per block (256 thr = 4 waves in 2x2), BK=64.
// LDS layout: row-major [row][64k], 128 B row stride (exactly 32 banks), with
// XOR swizzle: logical 16B-group g of row r lives at slot g ^ (r & 7).
// Staging keeps LDS linear (global_load_lds requires base+lane*16) and
// permutes the GLOBAL source address instead. Read side: 16 lanes of a
// ds_read_b128 land 2 lanes/bank -> conflict-free (m136: 2-way is free).
// ---------------------------------------------------------------------------
template<int TM, int TN>
__global__ __launch_bounds__(256) void gemm_t(
    const f16* __restrict__ A, const f16* __restrict__ Bt,
    float* __restrict__ C, const float* __restrict__ bias,
    int K, int ldc, int Nstore)
{
    constexpr int BK = 64;
    constexpr int AM = TM / 32;       // 16-row tiles per wave (m)
    constexpr int AN = TN / 32;       // 16-col tiles per wave (n)
    constexpr int CA = TM * 8;        // A 16B-chunks per K-tile
    constexpr int CB = TN * 8;
    constexpr int RTOT = (CA + CB) / 256;

    __shared__ f16 As[TM * BK];
    __shared__ f16 Bs[TN * BK];

    const int tid  = threadIdx.x;
    const int lane = tid & 63;
    const int w    = tid >> 6;
    const int wm   = (w >> 1) * (TM / 2);
    const int wn   = (w & 1) * (TN / 2);
    const int row0 = blockIdx.x * TM;
    const int col0 = blockIdx.y * TN;
    const int quad = lane >> 4;
    const int r16  = lane & 15;

    f32x4 acc[AM][AN] = {};

    // per-round staging descriptors (compile-time A/B split: CA % 256 == 0)
    const f16* gsrc[RTOT];
    f16* ldst[RTOT];
#pragma unroll
    for (int r = 0; r < RTOT; ++r) {
        int c = tid + r * 256;
        bool isA = (c < CA);
        int cc = isA ? c : c - CA;
        int row = cc >> 3;
        int gs = (cc & 7) ^ (row & 7);        // swizzled source group
        gsrc[r] = (isA ? A + (size_t)(row0 + row) * K
                       : Bt + (size_t)(col0 + row) * K) + gs * 8;
        ldst[r] = (isA ? As : Bs) + cc * 8;   // LDS stays linear
    }

    for (int k0 = 0; k0 < K; k0 += BK) {
#pragma unroll
        for (int r = 0; r < RTOT; ++r)
            load_lds16(gsrc[r] + k0, ldst[r]);
        __syncthreads();

#pragma unroll
        for (int ks = 0; ks < 2; ++ks) {
            f16x8 af[AM], bq[AN];
#pragma unroll
            for (int mi = 0; mi < AM; ++mi) {
                int row = wm + mi * 16 + r16;
                int slot = (ks * 4 + quad) ^ (r16 & 7);
                af[mi] = *(const f16x8*)&As[row * BK + slot * 8];
            }
#pragma unroll
            for (int ni = 0; ni < AN; ++ni) {
                int row = wn + ni * 16 + r16;
                int slot = (ks * 4 + quad) ^ (r16 & 7);
                bq[ni] = *(const f16x8*)&Bs[row * BK + slot * 8];
            }
#pragma unroll
            for (int mi = 0; mi < AM; ++mi)
#pragma unroll
                for (int ni = 0; ni < AN; ++ni)
                    acc[mi][ni] = __builtin_amdgcn_mfma_f32_16x16x32_f16(
                        af[mi], bq[ni], acc[mi][ni], 0, 0, 0);
        }
        __syncthreads();
    }

    // C/D layout: col = lane&15, row = quad*4 + reg
#pragma unroll
    for (int mi = 0; mi < AM; ++mi) {
#pragma unroll
        for (int ni = 0; ni < AN; ++ni) {
            int col = col0 + wn + ni * 16 + r16;
            if (col < Nstore) {
                float bv = bias ? bias[col] : 0.0f;
                int rowb = row0 + wm + mi * 16 + quad * 4;
#pragma unroll
                for (int r = 0; r < 4; ++r)
                    C[(size_t)(rowb + r) * ldc + col] = acc[mi][ni][r] + bv;
            }
        }
    }
}

// ---------------------------------------------------------------------------
__global__ void zero_k(float* __restrict__ p, int n) {
    int i = blockIdx.x * 256 + threadIdx.x;
    if (i < n) p[i] = 0.0f;
}

__global__ void f32_to_f16_k(const float* __restrict__ in, f16* __restrict__ out, int n4) {
    int i = blockIdx.x * 256 + threadIdx.x;
    if (i >= n4) return;
    float4 v = *(const float4*)&in[(size_t)i * 4];
    f16x4 o = {(f16)v.x, (f16)v.y, (f16)v.z, (f16)v.w};
    *(f16x4*)&out[(size_t)i * 4] = o;
}

// in [R,C] fp32 -> out [C,R] fp16 (coalesced writes, strided reads via L2)
__global__ void transpose_to_f16_k(const float* __restrict__ in, f16* __restrict__ out, int R, int C) {
    int idx = blockIdx.x * 256 + threadIdx.x;
    if (idx >= R * C) return;
    int n = idx / R, k = idx - n * R;
    out[idx] = (f16)in[(size_t)k * C + n];
}

// column sums/sumsq of h [4096,512]; 128 blocks x 256 thr, 2 cols/thread
__global__ void bn_stats_k(const float* __restrict__ h, float* __restrict__ sums, float* __restrict__ sqs) {
    int t = threadIdx.x, b = blockIdx.x;
    int c = t * 2;
    float s0 = 0.f, s1 = 0.f, q0 = 0.f, q1 = 0.f;
    for (int r = b; r < NROWS; r += 128) {
        float2 v = *(const float2*)&h[(size_t)r * DMLP + c];
        s0 += v.x; s1 += v.y; q0 += v.x * v.x; q1 += v.y * v.y;
    }
    atomicAdd(&sums[c], s0);
    atomicAdd(&sums[c + 1], s1);
    atomicAdd(&sqs[c], q0);
    atomicAdd(&sqs[c + 1], q1);
}

// fold BN stats into per-column scale/shift (512 threads total)
__global__ void bn_finish_k(const float* __restrict__ sums, const float* __restrict__ sqs,
                            const float* __restrict__ gamma, const float* __restrict__ beta,
                            float* __restrict__ scale, float* __restrict__ shift) {
    int c = blockIdx.x * 256 + threadIdx.x;
    if (c >= DMLP) return;
    const float inv_n = 1.0f / 4096.0f;
    float mu = sums[c] * inv_n;
    float var = fmaxf(sqs[c] * inv_n - mu * mu, 0.0f);
    float a = rsqrtf(var + 1e-5f) * gamma[c];
    scale[c] = a;
    shift[c] = beta[c] - mu * a;
}

// BN apply + ReLU + cast to fp16; 4 elems/thread (float4)
__global__ void bn_apply_k(const float* __restrict__ h, const float* __restrict__ scale,
                           const float* __restrict__ shift, f16* __restrict__ out) {
    int i = blockIdx.x * 256 + threadIdx.x;     // over 4096*512/4
    int c = (i & 127) * 4;
    float4 v = *(const float4*)&h[(size_t)i * 4];
    float4 sc = *(const float4*)&scale[c];
    float4 sh = *(const float4*)&shift[c];
    f16x4 o = {(f16)fmaxf(v.x * sc.x + sh.x, 0.0f),
               (f16)fmaxf(v.y * sc.y + sh.y, 0.0f),
               (f16)fmaxf(v.z * sc.z + sh.z, 0.0f),
               (f16)fmaxf(v.w * sc.w + sh.w, 0.0f)};
    *(f16x4*)&out[(size_t)i * 4] = o;
}

// row-wise L2 normalize out2[4096,256] -> feat fp32 + fp16; one wave/row
__global__ void l2norm_k(const float* __restrict__ X, float* __restrict__ Y, f16* __restrict__ Yh) {
    int wv = (blockIdx.x * 256 + threadIdx.x) >> 6;
    int lane = threadIdx.x & 63;
    float4 v = *(const float4*)&X[(size_t)wv * FDIM + lane * 4];
    float s = v.x * v.x + v.y * v.y + v.z * v.z + v.w * v.w;
#pragma unroll
    for (int off = 32; off > 0; off >>= 1) s += __shfl_xor(s, off);
    float inv = 1.0f / fmaxf(sqrtf(s), 1e-12f);
    float4 o = {v.x * inv, v.y * inv, v.z * inv, v.w * inv};
    *(float4*)&Y[(size_t)wv * FDIM + lane * 4] = o;
    f16x4 oh = {(f16)o.x, (f16)o.y, (f16)o.z, (f16)o.w};
    *(f16x4*)&Yh[(size_t)wv * FDIM + lane * 4] = oh;
}

// per-label sequential momentum chain + f16 memory-bank materialization.
// One wave per padded row; rows >= NCLS -> zeros; untouched rows -> cast(mp).
__global__ void chain_k(const int* __restrict__ label, const float* __restrict__ feat,
                        const float* __restrict__ mp, f16* __restrict__ memh) {
    int y = (blockIdx.x * 256 + threadIdx.x) >> 6;
    int lane = threadIdx.x & 63;
    float4 m = {0.f, 0.f, 0.f, 0.f};
    if (y < NCLS) {
        m = *(const float4*)&mp[(size_t)y * FDIM + lane * 4];
        for (int g = 0; g < 64; ++g) {
            int lab = label[g * 64 + lane];
            unsigned long long mask = __ballot(lab == y);
            while (mask) {
                int b = __builtin_ctzll(mask);
                mask &= mask - 1;
                int i = g * 64 + b;
                float4 x = *(const float4*)&feat[(size_t)i * FDIM + lane * 4];
                m.x = 0.9f * m.x + 0.1f * x.x;
                m.y = 0.9f * m.y + 0.1f * x.y;
                m.z = 0.9f * m.z + 0.1f * x.z;
                m.w = 0.9f * m.w + 0.1f * x.w;
                float s = m.x * m.x + m.y * m.y + m.z * m.z + m.w * m.w;
#pragma unroll
                for (int off = 32; off > 0; off >>= 1) s += __shfl_xor(s, off);
                float inv = 1.0f / fmaxf(sqrtf(s), 1e-12f);
                m.x *= inv; m.y *= inv; m.z *= inv; m.w *= inv;
            }
        }
    }
    f16x4 o = {(f16)m.x, (f16)m.y, (f16)m.z, (f16)m.w};
    *(f16x4*)&memh[(size_t)y * FDIM + lane * 4] = o;
}

// ---------------------------------------------------------------------------
extern "C" void kernel_launch(void* const* d_in, const int* in_sizes, int n_in,
                              void* d_out, int out_size, void* d_ws, size_t ws_size,
                              hipStream_t stream) {
    const float* feat_in = (const float*)d_in[0];
    const int*   label   = (const int*)d_in[1];
    const float* W1      = (const float*)d_in[2];
    const float* b1      = (const float*)d_in[3];
    const float* gamma   = (const float*)d_in[4];
    const float* beta    = (const float*)d_in[5];
    const float* W2      = (const float*)d_in[6];
    const float* b2      = (const float*)d_in[7];
    const float* mp      = (const float*)d_in[8];
    float* out = (float*)d_out;

    char* w = (char*)d_ws;
    f16* A1h   = (f16*)w;   w += (size_t)NROWS * DIMIN * 2;   // 12.6 MB
    f16* W1t   = (f16*)w;   w += (size_t)DMLP * DIMIN * 2;    // 1.6 MB
    f16* W2t   = (f16*)w;   w += (size_t)FDIM * DMLP * 2;     // 0.26 MB
    float* h   = (float*)w; w += (size_t)NROWS * DMLP * 4;    // 8.4 MB
    f16* h2    = (f16*)w;   w += (size_t)NROWS * DMLP * 2;    // 4.2 MB
    float* out2= (float*)w; w += (size_t)NROWS * FDIM * 4;    // 4.2 MB
    float* feat= (float*)w; w += (size_t)NROWS * FDIM * 4;    // 4.2 MB
    f16* feath = (f16*)w;   w += (size_t)NROWS * FDIM * 2;    // 2.1 MB
    f16* memh  = (f16*)w;   w += (size_t)NPAD * FDIM * 2;     // 5.2 MB
    float* sums= (float*)w; w += DMLP * 4;
    float* sqs = (float*)w; w += DMLP * 4;
    float* bnsc= (float*)w; w += DMLP * 4;
    float* bnsh= (float*)w; w += DMLP * 4;

    // stage 0: conversions + stat zeroing
    zero_k<<<4, 256, 0, stream>>>(sums, 2 * DMLP);   // sums+sqs contiguous
    f32_to_f16_k<<<(NROWS * DIMIN / 4) / 256, 256, 0, stream>>>(feat_in, A1h, NROWS * DIMIN / 4);
    transpose_to_f16_k<<<(DIMIN * DMLP) / 256, 256, 0, stream>>>(W1, W1t, DIMIN, DMLP);
    transpose_to_f16_k<<<(DMLP * FDIM) / 256, 256, 0, stream>>>(W2, W2t, DMLP, FDIM);

    // GEMM1: h = feat_in @ W1 + b1   (64x64 tiles -> 512 blocks)
    {
        dim3 g(NROWS / 64, DMLP / 64);
        gemm_t<64, 64><<<g, 256, 0, stream>>>(A1h, W1t, h, b1, DIMIN, DMLP, DMLP);
    }

    // BN
    bn_stats_k<<<128, 256, 0, stream>>>(h, sums, sqs);
    bn_finish_k<<<2, 256, 0, stream>>>(sums, sqs, gamma, beta, bnsc, bnsh);
    bn_apply_k<<<(NROWS * DMLP / 4) / 256, 256, 0, stream>>>(h, bnsc, bnsh, h2);

    // GEMM2: out2 = h2 @ W2 + b2    (64x64 tiles -> 256 blocks)
    {
        dim3 g(NROWS / 64, FDIM / 64);
        gemm_t<64, 64><<<g, 256, 0, stream>>>(h2, W2t, out2, b2, DMLP, FDIM, FDIM);
    }

    // feat = l2norm(out2)
    l2norm_k<<<NROWS / 4, 256, 0, stream>>>(out2, feat, feath);

    // memory bank: per-label chains + f16 materialization (pad rows zeroed)
    chain_k<<<NPAD / 4, 256, 0, stream>>>(label, feat, mp, memh);

    // GEMM3: sim = feat @ mem^T   [4096, 10000]  (128x128 tiles -> 2528 blocks)
    {
        dim3 g(NROWS / 128, NPAD / 128);
        gemm_t<128, 128><<<g, 256, 0, stream>>>(feath, memh, out, nullptr, FDIM, NCLS, NCLS);
    }
}